// Round 4
// baseline (439.584 us; speedup 1.0000x reference)
//
#include <hip/hip_runtime.h>

#define B_ROWS 4096
#define T_LEN  8192
#define GAMMA  0.99f
#define COEF   0.9405f   /* 0.99 * 0.95 */
#define CHUNK  512       /* 64 lanes * 8 elements */
#define SEG    4096      /* one truncation boundary; 8192 waves = full residency */
#define HALO   512       /* multiple of CHUNK; truncation c^512 ~ 2e-14 */
#define NSEG   (T_LEN / SEG)   /* 2 */

__device__ __forceinline__ float bcast0(float x) {
    return __uint_as_float(__builtin_amdgcn_readfirstlane(__float_as_uint(x)));
}

__global__ __launch_bounds__(256) void gae_kernel(
    const float* __restrict__ rewards,
    const float* __restrict__ values,
    float* __restrict__ adv,
    float* __restrict__ tgt)
{
    const int gw   = (int)((blockIdx.x * blockDim.x + threadIdx.x) >> 6);
    const int lane = (int)(threadIdx.x & 63);
    const int row  = gw >> 1;          // NSEG = 2 segments per row
    const int seg  = gw & 1;
    if (row >= B_ROWS) return;

    const int s0       = seg * SEG;
    const int halo_end = min(s0 + SEG + HALO, T_LEN);

    const float* r_row = rewards + (size_t)row * T_LEN;
    const float* v_row = values  + (size_t)row * (T_LEN + 1);
    float* a_row = adv + (size_t)row * T_LEN;
    float* t_row = tgt + (size_t)row * T_LEN;

    const float c2 = COEF * COEF;
    const float c4 = c2 * c2;
    const float c8 = c4 * c4;

    float carry        = 0.0f;             // truncated: exact for last segment
    float v_next_first = v_row[halo_end];  // V at the first element past this chunk

    int t0 = halo_end - CHUNK;
    int base = t0 + 8 * lane;
    float4 rlo = *(const float4*)(r_row + base);
    float4 rhi = *(const float4*)(r_row + base + 4);
    float v0 = v_row[base + 0];
    float v1 = v_row[base + 1];
    float v2 = v_row[base + 2];
    float v3 = v_row[base + 3];
    float v4 = v_row[base + 4];
    float v5 = v_row[base + 5];
    float v6 = v_row[base + 6];
    float v7 = v_row[base + 7];

    for (; t0 >= s0; t0 -= CHUNK) {
        // ---- prefetch next (earlier-in-time) chunk ----
        float4 rln = make_float4(0.f, 0.f, 0.f, 0.f);
        float4 rhn = make_float4(0.f, 0.f, 0.f, 0.f);
        float n0 = 0.f, n1 = 0.f, n2 = 0.f, n3 = 0.f;
        float n4 = 0.f, n5 = 0.f, n6 = 0.f, n7 = 0.f;
        const int tn = t0 - CHUNK;
        if (tn >= s0) {
            const int bn = tn + 8 * lane;
            rln = *(const float4*)(r_row + bn);
            rhn = *(const float4*)(r_row + bn + 4);
            n0 = v_row[bn + 0];
            n1 = v_row[bn + 1];
            n2 = v_row[bn + 2];
            n3 = v_row[bn + 3];
            n4 = v_row[bn + 4];
            n5 = v_row[bn + 5];
            n6 = v_row[bn + 6];
            n7 = v_row[bn + 7];
        }

        // ---- V_{t+1} for the lane's last element ----
        float v8 = __shfl_down(v0, 1);
        if (lane == 63) v8 = v_next_first;

        // ---- deltas ----
        const float d0 = fmaf(GAMMA, v1, rlo.x) - v0;
        const float d1 = fmaf(GAMMA, v2, rlo.y) - v1;
        const float d2 = fmaf(GAMMA, v3, rlo.z) - v2;
        const float d3 = fmaf(GAMMA, v4, rlo.w) - v3;
        const float d4 = fmaf(GAMMA, v5, rhi.x) - v4;
        const float d5 = fmaf(GAMMA, v6, rhi.y) - v5;
        const float d6 = fmaf(GAMMA, v7, rhi.z) - v6;
        const float d7 = fmaf(GAMMA, v8, rhi.w) - v7;

        // ---- in-lane suffix scan with zero carry ----
        const float a7l = d7;
        const float a6l = fmaf(COEF, a7l, d6);
        const float a5l = fmaf(COEF, a6l, d5);
        const float a4l = fmaf(COEF, a5l, d4);
        const float a3l = fmaf(COEF, a4l, d3);
        const float a2l = fmaf(COEF, a3l, d2);
        const float a1l = fmaf(COEF, a2l, d1);
        const float a0l = fmaf(COEF, a1l, d0);

        // ---- wave suffix composition of affines h_i(x) = P_i + c^8 * x ----
        float a = a0l;
        float b = c8;
        #pragma unroll
        for (int dlt = 1; dlt < 64; dlt <<= 1) {
            const float ar = __shfl_down(a, dlt);
            const float br = __shfl_down(b, dlt);
            if (lane + dlt < 64) {
                a = fmaf(b, ar, a);
                b = b * br;
            }
        }
        const float A0_aff = fmaf(b, carry, a);

        // lane carry-in: A at position 8(i+1)
        float cl = __shfl_down(A0_aff, 1);
        if (lane == 63) cl = carry;

        // ---- exact in-lane chain with real carry ----
        const float A7 = fmaf(COEF, cl, d7);
        const float A6 = fmaf(COEF, A7, d6);
        const float A5 = fmaf(COEF, A6, d5);
        const float A4 = fmaf(COEF, A5, d4);
        const float A3 = fmaf(COEF, A4, d3);
        const float A2 = fmaf(COEF, A3, d2);
        const float A1 = fmaf(COEF, A2, d1);
        const float A0 = fmaf(COEF, A1, d0);

        // ---- stores: only inside the owned segment (halo chunks skipped) ----
        // Plain stores (write-through L2): NT stores regressed 100->166us (round 1).
        if (t0 < s0 + SEG) {
            const int sb = t0 + 8 * lane;
            *(float4*)(a_row + sb)     = make_float4(A0, A1, A2, A3);
            *(float4*)(a_row + sb + 4) = make_float4(A4, A5, A6, A7);
            *(float4*)(t_row + sb)     = make_float4(v0 + A0, v1 + A1, v2 + A2, v3 + A3);
            *(float4*)(t_row + sb + 4) = make_float4(v4 + A4, v5 + A5, v6 + A6, v7 + A7);
        }

        // ---- propagate carries (scalar broadcast, off the DS critical path) ----
        carry        = bcast0(A0);
        v_next_first = bcast0(v0);

        // ---- rotate prefetch ----
        rlo = rln; rhi = rhn;
        v0 = n0; v1 = n1; v2 = n2; v3 = n3;
        v4 = n4; v5 = n5; v6 = n6; v7 = n7;
    }
}

extern "C" void kernel_launch(void* const* d_in, const int* in_sizes, int n_in,
                              void* d_out, int out_size, void* d_ws, size_t ws_size,
                              hipStream_t stream) {
    const float* rewards = (const float*)d_in[0];
    const float* values  = (const float*)d_in[1];
    float* adv = (float*)d_out;                       // advantages [B, T]
    float* tgt = adv + (size_t)B_ROWS * T_LEN;        // targets    [B, T]

    const int threads = 256;                          // 4 waves/block
    const int total_waves = B_ROWS * NSEG;            // one wave per (row, segment)
    const int blocks  = (total_waves * 64) / threads; // 2048 blocks = 8 per CU
    gae_kernel<<<blocks, threads, 0, stream>>>(rewards, values, adv, tgt);
}